// Round 11
// baseline (1302.764 us; speedup 1.0000x reference)
//
#include <hip/hip_runtime.h>
#include <hip/hip_bf16.h>
#include <stdint.h>

// Problem constants (fixed by the reference)
#define NN   50000
#define RR   50
#define BB   30
#define DIN  64
#define EE   1000000
#define KTOT 1984             // 30*64 + 64
#define NBW  8                // nodes per workgroup; 50000 = 6250*8 exactly
#define SR   65               // s row stride (floats) — breaks 4-way fold-read conflicts
#define SNODE (RR*SR)         // 3250 floats per node
#define TROW 2008             // t row stride (shorts), 16B-aligned
#define CTR  72               // ct row stride (shorts)

// LDS layout (bytes): s | t | ct | alpha  = 142,784 total (<160K)
#define OFF_T   104000        // 8*3250*4
#define OFF_CT  136128        // +8*2008*2
#define OFF_AL  140736        // +32*72*2
#define LDS_SZ  142784        // +8*64*4

typedef __attribute__((ext_vector_type(8))) short short8;
typedef __attribute__((ext_vector_type(4))) float floatx4;

#define RFL(x) __builtin_amdgcn_readfirstlane(x)

__device__ __forceinline__ float bf2f(unsigned short u) {
    return __int_as_float(((int)u) << 16);
}
__device__ __forceinline__ short f2bf(float f) {
    __hip_bfloat16 h = __float2bfloat16(f);
    return *reinterpret_cast<const short*>(&h);
}

// ---------------- preprocessing: counting sort of edges by dst ----------------

__global__ void k_hist(const int* __restrict__ dst, const int* __restrict__ et,
                       int* __restrict__ cnt, int* __restrict__ dcount) {
    int e = blockIdx.x * 256 + threadIdx.x;
    if (e < EE) {
        int d = dst[e], r = et[e];
        atomicAdd(&cnt[d * RR + r], 1);
        atomicAdd(&dcount[d], 1);
    }
}

__global__ void k_scan1(const int* __restrict__ dcount, int* __restrict__ doff,
                        int* __restrict__ bsum) {
    __shared__ int sh[256];
    int t = threadIdx.x;
    int i = blockIdx.x * 256 + t;
    int v = (i < NN) ? dcount[i] : 0;
    sh[t] = v;
    __syncthreads();
    for (int s = 1; s < 256; s <<= 1) {
        int add = (t >= s) ? sh[t - s] : 0;
        __syncthreads();
        sh[t] += add;
        __syncthreads();
    }
    int incl = sh[t];
    if (i < NN) doff[i] = incl - v;
    if (t == 255) bsum[blockIdx.x] = incl;
}

__global__ void k_scan2(int* __restrict__ bsum, int nbv) {
    __shared__ int sh[256];
    int t = threadIdx.x;
    int v = (t < nbv) ? bsum[t] : 0;
    sh[t] = v;
    __syncthreads();
    for (int s = 1; s < 256; s <<= 1) {
        int add = (t >= s) ? sh[t - s] : 0;
        __syncthreads();
        sh[t] += add;
        __syncthreads();
    }
    if (t < nbv) bsum[t] = sh[t] - v;
}

__global__ void k_scan3(int* __restrict__ doff, const int* __restrict__ bsum) {
    int i = blockIdx.x * 256 + threadIdx.x;
    if (i < NN) doff[i] += bsum[blockIdx.x];
}

// records are just {src, rel}; alpha folds in later from the cnt table
__global__ void k_scatter(const int* __restrict__ src, const int* __restrict__ dst,
                          const int* __restrict__ et,
                          const int* __restrict__ doff, int* __restrict__ cursor,
                          int2* __restrict__ rec2) {
    int e = blockIdx.x * 256 + threadIdx.x;
    if (e < EE) {
        int d = dst[e];
        int p = doff[d] + atomicAdd(&cursor[d], 1);
        rec2[p] = make_int2(src[e], et[e]);
    }
}

__global__ void k_cast_x(const float* __restrict__ x, short* __restrict__ h) {
    int i = blockIdx.x * 256 + threadIdx.x;
    if (i < NN * DIN) h[i] = f2bf(x[i]);
}

// comp^T tables, bf16: ct[l][b][r], b<30 & r<50 valid, else 0. [3][32][72]
__global__ void k_prep_ct3(const float* __restrict__ c0, const float* __restrict__ c1,
                           const float* __restrict__ c2, short* __restrict__ ct) {
    int idx = blockIdx.x * 256 + threadIdx.x;
    if (idx < 3 * 32 * CTR) {
        int l = idx / (32 * CTR);
        int rem = idx - l * (32 * CTR);
        int b = rem / CTR, r = rem - b * CTR;
        const float* c = (l == 0) ? c0 : (l == 1) ? c1 : c2;
        float v = (b < BB && r < RR) ? c[r * BB + b] : 0.f;
        ct[idx] = f2bf(v);
    }
}

// transposed bf16 weights: rows [0,64) L0; [64,128) L1; [128,144) L2 (dout=8 padded)
__global__ void k_prep_w3(const float* __restrict__ b0, const float* __restrict__ r0,
                          const float* __restrict__ b1, const float* __restrict__ r1,
                          const float* __restrict__ b2, const float* __restrict__ r2,
                          short* __restrict__ wt) {
    int idx = blockIdx.x * 256 + threadIdx.x;
    if (idx >= 144 * KTOT) return;
    int row = idx / KTOT, k = idx - row * KTOT;
    const float* bs; const float* rt; int o, dout;
    if (row < 64)       { bs = b0; rt = r0; o = row;        dout = 64; }
    else if (row < 128) { bs = b1; rt = r1; o = row - 64;   dout = 64; }
    else                { bs = b2; rt = r2; o = row - 128;  dout = 8;  }
    float v = 0.f;
    if (o < dout)
        v = (k < BB * DIN) ? bs[k * dout + o] : rt[(k - BB * DIN) * dout + o];
    wt[idx] = f2bf(v);
}

// ---------------- fused per-layer kernel ----------------
// 512 threads = 8 waves, 8 nodes, 1 block/CU (142.8KB LDS).
// Phase A: wave wv owns node wv. Per 2-edge pair: coalesced x gathers (prefetched
//   2 pairs ahead), scalar rel-equality check, LDS fp32 rmw into s[node][rel][feat].
// Phase B: per-node MFMA fold t(30x64) = comp^T(32x64K) * (alpha.s)(64Kx64),
//   16x16x32 bf16, C regs -> t_tile (t region disjoint from s).
// Phase C: R7-style K=1984 GEMM (M=8 padded to 16) + LDS reduction; layer-2
//   fuses log_softmax via octet shuffles.
template <int DOUT, bool RELU>
__global__ __launch_bounds__(512, 2)
void k_fused(const short* __restrict__ xin,          // bf16 bits
             const int2* __restrict__ rec2,
             const int* __restrict__ doff, const int* __restrict__ dcount,
             const int* __restrict__ cntt,           // [N][50]
             const short* __restrict__ ctb,          // [32][72] bf16 comp^T
             const short* __restrict__ Wt,           // [DPAD][KTOT] bf16
             const float* __restrict__ bias,
             void* __restrict__ outp) {
    __shared__ __align__(16) char smem[LDS_SZ];
    float* s_lds   = (float*)smem;
    short* t_tile  = (short*)(smem + OFF_T);
    short* ct_lds  = (short*)(smem + OFF_CT);
    float* al_lds  = (float*)(smem + OFF_AL);

    const int tid  = threadIdx.x;
    const int lane = tid & 63;
    const int wv   = RFL(tid >> 6);          // 0..7 = node
    const int node0 = blockIdx.x * NBW;
    const int n    = node0 + wv;

    // stage comp^T (32*72 shorts = 1152 ints)
    for (int i = tid; i < (32 * CTR) / 2; i += 512)
        ((int*)ct_lds)[i] = ((const int*)ctb)[i];

    // ---- phase A ----
    {
        float* srow = s_lds + wv * SNODE;
        // zero s rows
        for (int r = 0; r < RR; ++r) srow[r * SR + lane] = 0.f;
        // alpha[wv][k] = 1/cnt (k<50, cnt>0) else 0
        float av = 0.f;
        if (lane < RR) {
            int c = cntt[(size_t)n * RR + lane];
            av = (c > 0) ? (1.0f / (float)c) : 0.f;
        }
        if (lane < 64) al_lds[wv * 64 + lane] = av;

        const int beg = RFL(doff[n]), cnt = RFL(dcount[n]);
        const int2* rp = rec2 + beg;
        const int np = cnt >> 1;
        if (np > 0) {
            // pair 0 in regs
            int2 eA = rp[0], eB = rp[1];
            int ra0 = RFL(eA.y), rb0 = RFL(eB.y);
            float xa0 = bf2f((unsigned short)xin[RFL(eA.x) * DIN + lane]);
            float xb0 = bf2f((unsigned short)xin[RFL(eB.x) * DIN + lane]);
            // pair 1 (clamped)
            const int i1 = (np > 1) ? 2 : 0;
            int2 fA = rp[i1], fB = rp[i1 + 1];
            int ra1 = RFL(fA.y), rb1 = RFL(fB.y);
            float xa1 = bf2f((unsigned short)xin[RFL(fA.x) * DIN + lane]);
            float xb1 = bf2f((unsigned short)xin[RFL(fB.x) * DIN + lane]);

            for (int p = 0; p < np; ++p) {
                // prefetch pair p+2 (clamped)
                int i2 = p + 2; if (i2 > np - 1) i2 = np - 1;
                int2 gA = rp[2 * i2], gB = rp[2 * i2 + 1];
                int ra2 = RFL(gA.y), rb2 = RFL(gB.y);
                float xa2 = bf2f((unsigned short)xin[RFL(gA.x) * DIN + lane]);
                float xb2 = bf2f((unsigned short)xin[RFL(gB.x) * DIN + lane]);
                // rmw current pair (wave-uniform branch on rel equality)
                if (ra0 == rb0) {
                    srow[ra0 * SR + lane] += xa0 + xb0;
                } else {
                    float u = srow[ra0 * SR + lane];
                    float v = srow[rb0 * SR + lane];
                    srow[ra0 * SR + lane] = u + xa0;
                    srow[rb0 * SR + lane] = v + xb0;
                }
                // rotate
                ra0 = ra1; rb0 = rb1; xa0 = xa1; xb0 = xb1;
                ra1 = ra2; rb1 = rb2; xa1 = xa2; xb1 = xb2;
            }
        }
        if (cnt & 1) {
            int2 eL = rp[cnt - 1];
            int rl = RFL(eL.y);
            float xl = bf2f((unsigned short)xin[RFL(eL.x) * DIN + lane]);
            srow[rl * SR + lane] += xl;
        }
        // self/root row of t (k = 1920..1983)
        t_tile[wv * TROW + BB * DIN + lane] = xin[(size_t)n * DIN + lane];
    }
    __syncthreads();

    // ---- phase B: per-node fold t = comp^T * (alpha .* s), MFMA 16x16x32 ----
    {
        const int mm = lane & 15;
        const int qq = lane >> 4;
        const float* sbase = s_lds + wv * SNODE;
        const float* abase = al_lds + wv * 64;
        // cache A-frags: [mt][s2]
        short8 afr[2][2];
#pragma unroll
        for (int mt = 0; mt < 2; ++mt)
#pragma unroll
            for (int s2 = 0; s2 < 2; ++s2)
                afr[mt][s2] = *(const short8*)(ct_lds + (mt * 16 + mm) * CTR
                                               + s2 * 32 + qq * 8);
#pragma unroll
        for (int nt = 0; nt < 4; ++nt) {
            const int f = nt * 16 + mm;
            // B-frags for both K-steps
            short8 bfr[2];
#pragma unroll
            for (int s2 = 0; s2 < 2; ++s2) {
#pragma unroll
                for (int t = 0; t < 8; ++t) {
                    const int k = s2 * 32 + qq * 8 + t;
                    float sv = (k < RR) ? sbase[k * SR + f] : 0.f;
                    bfr[s2][t] = f2bf(sv * abase[k]);
                }
            }
#pragma unroll
            for (int mt = 0; mt < 2; ++mt) {
                floatx4 p = {0.f, 0.f, 0.f, 0.f};
                p = __builtin_amdgcn_mfma_f32_16x16x32_bf16(afr[mt][0], bfr[0], p, 0, 0, 0);
                p = __builtin_amdgcn_mfma_f32_16x16x32_bf16(afr[mt][1], bfr[1], p, 0, 0, 0);
                // C/D: col=mm (=feature within nt), row=qq*4+r (=basis within mt)
#pragma unroll
                for (int r = 0; r < 4; ++r) {
                    const int b = mt * 16 + qq * 4 + r;
                    if (b < BB)
                        t_tile[wv * TROW + b * DIN + f] = f2bf(p[r]);
                }
            }
        }
    }
    __syncthreads();

    // ---- phase C: out = t(8xK,pad16) * Wt^T, K = 1984 (62 steps), 8 waves ----
    const int mm = lane & 15;
    const int qq = lane >> 4;
    int ct4, kp, kk0, nst;
    if (DOUT == 64) {
        ct4 = wv & 3; kp = wv >> 2;
        kk0 = kp * 31; nst = 31;
    } else {
        ct4 = 0; kp = wv;
        kk0 = (kp < 6) ? kp * 8 : 48 + (kp - 6) * 7;
        nst = (kp < 6) ? 8 : 7;
    }
    floatx4 p0 = {0.f, 0.f, 0.f, 0.f};
    {
        const short* arow = t_tile + mm * TROW + qq * 8;
        const short* wrow = Wt + (size_t)(ct4 * 16 + mm) * KTOT + qq * 8;
        for (int s = 0; s < nst; ++s) {
            const int kk = kk0 + s;
            short8 a = {0, 0, 0, 0, 0, 0, 0, 0};
            if (mm < NBW) a = *(const short8*)(arow + kk * 32);
            short8 w = *(const short8*)(wrow + kk * 32);
            p0 = __builtin_amdgcn_mfma_f32_16x16x32_bf16(a, w, p0, 0, 0, 0);
        }
    }
    float* red = s_lds;   // reuse s region (disjoint from t) for partials, stride 5

    if (DOUT == 64) {
        if (kp == 1) {
            const int off = (ct4 * 64 + lane) * 5;
#pragma unroll
            for (int i = 0; i < 4; ++i) red[off + i] = p0[i];
        }
        __syncthreads();
        if (kp == 0) {
            const int off = (ct4 * 64 + lane) * 5;
#pragma unroll
            for (int i = 0; i < 4; ++i) p0[i] += red[off + i];
            if (qq < 2) {
                const int o = ct4 * 16 + mm;
                const float bi = bias[o];
#pragma unroll
                for (int r = 0; r < 4; ++r) {
                    const int nn = node0 + qq * 4 + r;
                    float v = p0[r] + bi;
                    if (RELU) {
                        v = fmaxf(v, 0.f);
                        reinterpret_cast<short*>(outp)[(size_t)nn * DOUT + o] = f2bf(v);
                    } else {
                        reinterpret_cast<float*>(outp)[(size_t)nn * DOUT + o] = v;
                    }
                }
            }
        }
    } else {
        if (kp > 0) {
            const int off = ((kp - 1) * 64 + lane) * 5;
#pragma unroll
            for (int i = 0; i < 4; ++i) red[off + i] = p0[i];
        }
        __syncthreads();
        if (kp == 0) {
#pragma unroll
            for (int w = 0; w < 7; ++w) {
                const int off = (w * 64 + lane) * 5;
#pragma unroll
                for (int i = 0; i < 4; ++i) p0[i] += red[off + i];
            }
            const float bi = (mm < DOUT) ? bias[mm] : 0.f;
#pragma unroll
            for (int r = 0; r < 4; ++r) {
                float acc = p0[r] + bi;
                // log_softmax across the 8 cols (lanes mm 0..7 of this qq group)
                float m = acc;
                m = fmaxf(m, __shfl_xor(m, 1));
                m = fmaxf(m, __shfl_xor(m, 2));
                m = fmaxf(m, __shfl_xor(m, 4));
                float ex = expf(acc - m);
                float sm = ex;
                sm += __shfl_xor(sm, 1);
                sm += __shfl_xor(sm, 2);
                sm += __shfl_xor(sm, 4);
                float ls = logf(sm);
                if (qq < 2 && mm < DOUT) {
                    const int nn = node0 + qq * 4 + r;
                    reinterpret_cast<float*>(outp)[(size_t)nn * DOUT + mm] = acc - m - ls;
                }
            }
        }
    }
}

// ---------------- launch ----------------
extern "C" void kernel_launch(void* const* d_in, const int* in_sizes, int n_in,
                              void* d_out, int out_size, void* d_ws, size_t ws_size,
                              hipStream_t stream) {
    const float* x     = (const float*)d_in[0];
    const int*   eidx  = (const int*)d_in[1];
    const int*   etype = (const int*)d_in[2];
    const float* bases0 = (const float*)d_in[3];
    const float* comp0  = (const float*)d_in[4];
    const float* root0  = (const float*)d_in[5];
    const float* bias0  = (const float*)d_in[6];
    const float* bases1 = (const float*)d_in[7];
    const float* comp1  = (const float*)d_in[8];
    const float* root1  = (const float*)d_in[9];
    const float* bias1  = (const float*)d_in[10];
    const float* bases2 = (const float*)d_in[11];
    const float* comp2  = (const float*)d_in[12];
    const float* root2  = (const float*)d_in[13];
    const float* bias2  = (const float*)d_in[14];
    const int* srcp = eidx;
    const int* dstp = eidx + EE;

    char* p = (char*)d_ws;
    auto carve = [&](size_t bytes) -> char* {
        char* r = p;
        p += (bytes + 255) & ~(size_t)255;
        return r;
    };
    int*  cnt    = (int*)carve((size_t)NN * RR * sizeof(int));   // 10 MB (kept: alpha source)
    int*  dcount = (int*)carve((size_t)NN * sizeof(int));
    int*  cursor = (int*)carve((size_t)NN * sizeof(int));
    int*  doff   = (int*)carve((size_t)NN * sizeof(int));
    int*  bsum   = (int*)carve(256 * sizeof(int));
    int2* rec2   = (int2*)carve((size_t)EE * sizeof(int2));      // 8 MB
    short* h0    = (short*)carve((size_t)NN * DIN * 2);
    short* h1    = (short*)carve((size_t)NN * DIN * 2);
    short* h2    = (short*)carve((size_t)NN * DIN * 2);
    short* wtA   = (short*)carve((size_t)144 * KTOT * sizeof(short));
    short* ctA   = (short*)carve((size_t)3 * 32 * CTR * sizeof(short));

    // cnt, dcount, cursor adjacent -> one memset
    hipMemsetAsync(cnt, 0, (size_t)NN * (RR + 2) * sizeof(int) + 512, stream);

    const int EB = (EE + 255) / 256;   // 3907
    const int NB = (NN + 255) / 256;   // 196
    k_hist<<<EB, 256, 0, stream>>>(dstp, etype, cnt, dcount);
    k_scan1<<<NB, 256, 0, stream>>>(dcount, doff, bsum);
    k_scan2<<<1, 256, 0, stream>>>(bsum, NB);
    k_scan3<<<NB, 256, 0, stream>>>(doff, bsum);
    k_scatter<<<EB, 256, 0, stream>>>(srcp, dstp, etype, doff, cursor, rec2);
    k_cast_x<<<(NN * DIN + 255) / 256, 256, 0, stream>>>(x, h0);
    k_prep_ct3<<<(3 * 32 * CTR + 255) / 256, 256, 0, stream>>>(comp0, comp1, comp2, ctA);
    k_prep_w3<<<(144 * KTOT + 255) / 256, 256, 0, stream>>>(bases0, root0, bases1, root1,
                                                            bases2, root2, wtA);

    short* wt0 = wtA;
    short* wt1 = wtA + (size_t)64 * KTOT;
    short* wt2 = wtA + (size_t)128 * KTOT;
    short* ct0 = ctA;
    short* ct1 = ctA + 32 * CTR;
    short* ct2 = ctA + 2 * 32 * CTR;

    const int NF = NN / NBW;   // 6250 (exact)
    k_fused<64, true ><<<NF, 512, 0, stream>>>(h0, rec2, doff, dcount, cnt, ct0, wt0, bias0, (void*)h1);
    k_fused<64, true ><<<NF, 512, 0, stream>>>(h1, rec2, doff, dcount, cnt, ct1, wt1, bias1, (void*)h2);
    k_fused<8,  false><<<NF, 512, 0, stream>>>(h2, rec2, doff, dcount, cnt, ct2, wt2, bias2, d_out);
}